// Round 1
// baseline (371.090 us; speedup 1.0000x reference)
//
#include <hip/hip_runtime.h>
#include <hip/hip_bf16.h>

#define M_ROWS 16384
#define D_DIM  1024
#define K_CB   4096

#define MTILE  128
#define BN     64
#define BK     64
#define NSPLIT 4
#define COLS_PER_SPLIT (K_CB / NSPLIT)   // 1024
#define CHUNKS (COLS_PER_SPLIT / BN)     // 16
#define KSTEPS (D_DIM / BK)              // 16
#define GITERS (CHUNKS * KSTEPS)         // 256
#define MBLOCKS (M_ROWS / MTILE)         // 128

typedef __attribute__((ext_vector_type(8))) short short8;
typedef __attribute__((ext_vector_type(4))) float f32x4;

static __device__ __forceinline__ unsigned short f2bf(float f) {
  unsigned u = __float_as_uint(f);
  unsigned r = ((u >> 16) & 1u) + 0x7FFFu;   // RNE
  return (unsigned short)((u + r) >> 16);
}

// monotone float->u32 key (all finite floats ordered)
static __device__ __forceinline__ unsigned f2sortable(float f) {
  unsigned u = __float_as_uint(f);
  return (u & 0x80000000u) ? ~u : (u | 0x80000000u);
}

static __device__ __forceinline__ void gload_lds16(const unsigned short* g, unsigned short* l) {
  __builtin_amdgcn_global_load_lds(
      (const __attribute__((address_space(1))) void*)g,
      (__attribute__((address_space(3))) void*)l, 16, 0, 0);
}

// ---------------- Kernel 1: l2-normalize rows -> bf16 ----------------
__global__ __launch_bounds__(256)
void k_normalize(const float* __restrict__ z, const float* __restrict__ cb,
                 unsigned short* __restrict__ zf, unsigned short* __restrict__ cbf) {
  const int bid = blockIdx.x;
  const float* src;
  unsigned short* dst;
  if (bid < M_ROWS) {
    src = z + (size_t)bid * D_DIM;
    dst = zf + (size_t)bid * D_DIM;
  } else {
    const int r = bid - M_ROWS;
    src = cb + (size_t)r * D_DIM;
    dst = cbf + (size_t)r * D_DIM;
  }
  const int t = threadIdx.x;
  const float4 v = ((const float4*)src)[t];
  float ss = v.x * v.x + v.y * v.y + v.z * v.z + v.w * v.w;
#pragma unroll
  for (int off = 32; off > 0; off >>= 1) ss += __shfl_down(ss, off, 64);
  __shared__ float sp[4];
  if ((t & 63) == 0) sp[t >> 6] = ss;
  __syncthreads();
  const float tot = sp[0] + sp[1] + sp[2] + sp[3];
  const float invn = 1.0f / sqrtf(tot + 1e-12f);
  ushort4 o;
  o.x = f2bf(v.x * invn);
  o.y = f2bf(v.y * invn);
  o.z = f2bf(v.z * invn);
  o.w = f2bf(v.w * invn);
  ((ushort4*)dst)[t] = o;
}

// ---------------- Kernel 2: fused bf16 GEMM + per-row top-8 ----------------
__global__ __launch_bounds__(512, 4)
void k_gemm_topk(const unsigned short* __restrict__ zf,
                 const unsigned short* __restrict__ cbf,
                 unsigned* __restrict__ part) {
  __shared__ unsigned short sA[2][MTILE * BK];  // [row][8-elem slot], slot xor-swizzled by row&7
  __shared__ unsigned short sB[2][BN * BK];
  __shared__ unsigned sL[MTILE][33];            // 32-col logits staging / merge scratch (pad->2-way)

  const int tid  = threadIdx.x;
  const int lane = tid & 63;
  const int wid  = tid >> 6;
  const int wm   = wid >> 1;   // 0..3
  const int wn   = wid & 1;    // 0..1
  const int lo   = lane & 15;
  const int hi   = lane >> 4;

  const int mtile = blockIdx.x;
  const int split = blockIdx.y;
  const int rbase = mtile * MTILE;
  const int cbase = split * COLS_PER_SPLIT;

  // fragment LDS element offsets (A: row = wm*32+mi*16+lo, k-slot = kk*4+hi, xor row&7)
  int aoffs[2][2], boffs[2][2];
#pragma unroll
  for (int mi = 0; mi < 2; ++mi) {
    const int r = wm * 32 + mi * 16 + lo;
#pragma unroll
    for (int kk = 0; kk < 2; ++kk) {
      const int s = kk * 4 + hi;
      aoffs[mi][kk] = r * BK + ((s ^ (r & 7)) << 3);
    }
  }
#pragma unroll
  for (int nj = 0; nj < 2; ++nj) {
    const int c = wn * 32 + nj * 16 + lo;
#pragma unroll
    for (int kk = 0; kk < 2; ++kk) {
      const int s = kk * 4 + hi;
      boffs[nj][kk] = c * BK + ((s ^ (c & 7)) << 3);
    }
  }

  // staging geometry: slot sig -> row=sig>>3, s=sig&7; LDS linear dest sig*16B;
  // source pre-swizzled so LDS slot s holds global slot s^(row&7)
  const int stRow = tid >> 3;  // 0..63
  const int stS   = tid & 7;
  const long srcA0 = (long)(rbase + stRow) * D_DIM + ((stS ^ (stRow & 7)) << 3);
  // (stRow+64)&7 == stRow&7 -> second half = +64 rows
  const long srcB0 = (long)(cbase + stRow) * D_DIM + ((stS ^ (stRow & 7)) << 3);

  f32x4 acc[2][2];
#pragma unroll
  for (int mi = 0; mi < 2; ++mi)
#pragma unroll
    for (int nj = 0; nj < 2; ++nj) acc[mi][nj] = (f32x4){0.f, 0.f, 0.f, 0.f};

  unsigned tk[8];
#pragma unroll
  for (int q = 0; q < 8; ++q) tk[q] = 0u;
  unsigned tmin = 0u;

  auto STAGE = [&](int g1) {
    const int b = g1 & 1;
    const int ks = (g1 & (KSTEPS - 1)) * BK;
    const int chunk = g1 >> 4;
    gload_lds16(zf + srcA0 + ks, &sA[b][tid * 8]);
    gload_lds16(zf + srcA0 + (long)64 * D_DIM + ks, &sA[b][(tid + 512) * 8]);
    gload_lds16(cbf + srcB0 + (long)chunk * BN * D_DIM + ks, &sB[b][tid * 8]);
  };

  auto COMPUTE = [&](int b) {
    const unsigned short* A  = sA[b];
    const unsigned short* Bp = sB[b];
#pragma unroll
    for (int kk = 0; kk < 2; ++kk) {
      const short8 av0 = *(const short8*)(A + aoffs[0][kk]);
      const short8 av1 = *(const short8*)(A + aoffs[1][kk]);
      const short8 bv0 = *(const short8*)(Bp + boffs[0][kk]);
      const short8 bv1 = *(const short8*)(Bp + boffs[1][kk]);
      acc[0][0] = __builtin_amdgcn_mfma_f32_16x16x32_bf16(av0, bv0, acc[0][0], 0, 0, 0);
      acc[0][1] = __builtin_amdgcn_mfma_f32_16x16x32_bf16(av0, bv1, acc[0][1], 0, 0, 0);
      acc[1][0] = __builtin_amdgcn_mfma_f32_16x16x32_bf16(av1, bv0, acc[1][0], 0, 0, 0);
      acc[1][1] = __builtin_amdgcn_mfma_f32_16x16x32_bf16(av1, bv1, acc[1][1], 0, 0, 0);
    }
  };

  STAGE(0);
  __syncthreads();

  for (int g = 0; g < GITERS; ++g) {
    if (g + 1 < GITERS) STAGE(g + 1);
    COMPUTE(g & 1);
    __syncthreads();

    if ((g & (KSTEPS - 1)) == (KSTEPS - 1)) {
      const int chunk = g >> 4;
#pragma unroll
      for (int pass = 0; pass < 2; ++pass) {
        if (wn == pass) {
#pragma unroll
          for (int mi = 0; mi < 2; ++mi)
#pragma unroll
            for (int nj = 0; nj < 2; ++nj)
#pragma unroll
              for (int r = 0; r < 4; ++r)
                sL[wm * 32 + mi * 16 + hi * 4 + r][nj * 16 + lo] =
                    __float_as_uint(acc[mi][nj][r]);
        }
        __syncthreads();
        {
          const int row = tid >> 2, j = tid & 3;
          const int cg0 = cbase + chunk * BN + pass * 32 + j * 8;
#pragma unroll
          for (int i = 0; i < 8; ++i) {
            const float v = __uint_as_float(sL[row][j * 8 + i]);
            const unsigned key = (f2sortable(v) & ~0xFFFu) | (unsigned)(cg0 + i);
            if (key > tmin) {
              int ms = 0;
              unsigned mv = tk[0];
#pragma unroll
              for (int q = 1; q < 8; ++q) { if (tk[q] < mv) { mv = tk[q]; ms = q; } }
#pragma unroll
              for (int q = 0; q < 8; ++q) tk[q] = (q == ms) ? key : tk[q];
              mv = tk[0];
#pragma unroll
              for (int q = 1; q < 8; ++q) mv = (tk[q] < mv) ? tk[q] : mv;
              tmin = mv;
            }
          }
        }
        __syncthreads();
      }
#pragma unroll
      for (int mi = 0; mi < 2; ++mi)
#pragma unroll
        for (int nj = 0; nj < 2; ++nj) acc[mi][nj] = (f32x4){0.f, 0.f, 0.f, 0.f};
    }
  }

  // per-row merge of 4 thread-local top-8s -> split top-8
  {
    const int row = tid >> 2, j = tid & 3;
#pragma unroll
    for (int q = 0; q < 8; ++q) sL[row][j * 8 + q] = tk[q];
  }
  __syncthreads();
  if ((tid & 3) == 0) {
    const int row = tid >> 2;
    unsigned* dst = part + ((size_t)(rbase + row) * NSPLIT + split) * 8;
#pragma unroll
    for (int p = 0; p < 8; ++p) {
      unsigned best = 0;
      int bq = 0;
      for (int q = 0; q < 32; ++q) {
        const unsigned c = sL[row][q];
        if (c > best) { best = c; bq = q; }
      }
      sL[row][bq] = 0u;
      dst[p] = best;
    }
  }
}

// ---------------- Kernel 3: merge splits, softmax, gather E, gate ----------------
__global__ __launch_bounds__(256)
void k_gate(const unsigned* __restrict__ part, const float* __restrict__ target,
            const float* __restrict__ E, float* __restrict__ out) {
  const int row = blockIdx.x;
  const int t = threadIdx.x;
  __shared__ float s_alpha[8];
  __shared__ int s_idx[8];
  __shared__ unsigned s_key[8];

  if (t < 32) {
    unsigned k = part[(size_t)row * 32 + t];
#pragma unroll
    for (int p = 0; p < 8; ++p) {
      unsigned m = k;
#pragma unroll
      for (int off = 16; off > 0; off >>= 1) {
        const unsigned o = __shfl_xor(m, off, 32);
        m = (m > o) ? m : o;
      }
      if (k == m) { s_key[p] = k; k = 0u; }  // keys distinct (idx in low bits)
    }
  }
  __syncthreads();
  if (t < 8) {
    const unsigned key = s_key[t];
    unsigned ks = key & ~0xFFFu;
    unsigned vb = (ks & 0x80000000u) ? (ks ^ 0x80000000u) : ~ks;
    const float val = 10.0f * __uint_as_float(vb);
    unsigned ks0 = s_key[0] & ~0xFFFu;
    unsigned vb0 = (ks0 & 0x80000000u) ? (ks0 ^ 0x80000000u) : ~ks0;
    const float vmax = 10.0f * __uint_as_float(vb0);
    const float e = expf(val - vmax);
    float s = e;
#pragma unroll
    for (int off = 4; off > 0; off >>= 1) s += __shfl_xor(s, off, 8);
    s_alpha[t] = e / s;
    s_idx[t] = (int)(key & 0xFFFu);
  }
  __syncthreads();

  float4 g = {0.f, 0.f, 0.f, 0.f};
#pragma unroll
  for (int p = 0; p < 8; ++p) {
    const float a = s_alpha[p];
    const float4 e4 = ((const float4*)E)[(size_t)s_idx[p] * 256 + t];
    g.x += a * e4.x;
    g.y += a * e4.y;
    g.z += a * e4.z;
    g.w += a * e4.w;
  }
  const float4 tg = ((const float4*)target)[(size_t)row * 256 + t];
  float4 o;
  o.x = tg.x * (1.f + g.x);
  o.y = tg.y * (1.f + g.y);
  o.z = tg.z * (1.f + g.z);
  o.w = tg.w * (1.f + g.w);
  ((float4*)out)[(size_t)row * 256 + t] = o;
}

extern "C" void kernel_launch(void* const* d_in, const int* in_sizes, int n_in,
                              void* d_out, int out_size, void* d_ws, size_t ws_size,
                              hipStream_t stream) {
  const float* z      = (const float*)d_in[0];
  const float* target = (const float*)d_in[1];
  const float* cb     = (const float*)d_in[2];
  const float* E      = (const float*)d_in[3];
  float* out = (float*)d_out;

  // d_out doubles as scratch for the bf16 normalized matrices (dead before k_gate writes)
  unsigned short* zf  = (unsigned short*)d_out;                       // 32 MB
  unsigned short* cbf = (unsigned short*)((char*)d_out + 33554432);   // 8 MB @ +32MB
  unsigned* part = (unsigned*)d_ws;                                   // 2 MB (assumes ws_size >= 2MB)

  k_normalize<<<dim3(M_ROWS + K_CB), dim3(256), 0, stream>>>(z, cb, zf, cbf);
  k_gemm_topk<<<dim3(MBLOCKS, NSPLIT), dim3(512), 0, stream>>>(zf, cbf, part);
  k_gate<<<dim3(M_ROWS), dim3(256), 0, stream>>>(part, target, E, out);
}

// Round 3
// 356.183 us; speedup vs baseline: 1.0419x; 1.0419x over previous
//
#include <hip/hip_runtime.h>
#include <hip/hip_bf16.h>

#define M_ROWS 16384
#define D_DIM  1024
#define K_CB   4096

#define MTILE  128               // z rows per block
#define NTILE  128               // cb cols per chunk
#define BK     32
#define NSPLIT 4
#define COLS_PER_SPLIT (K_CB / NSPLIT)     // 1024
#define CHUNKS (COLS_PER_SPLIT / NTILE)    // 8
#define KSTEPS (D_DIM / BK)                // 32
#define GITERS (CHUNKS * KSTEPS)           // 256
#define MBLOCKS (M_ROWS / MTILE)           // 128

typedef __attribute__((ext_vector_type(8))) short short8;
typedef __attribute__((ext_vector_type(4))) float f32x4;

static __device__ __forceinline__ unsigned short f2bf(float f) {
  unsigned u = __float_as_uint(f);
  unsigned r = ((u >> 16) & 1u) + 0x7FFFu;   // RNE
  return (unsigned short)((u + r) >> 16);
}

// monotone float->u32 key (all finite floats ordered)
static __device__ __forceinline__ unsigned f2sortable(float f) {
  unsigned u = __float_as_uint(f);
  return (u & 0x80000000u) ? ~u : (u | 0x80000000u);
}

static __device__ __forceinline__ float sortable2f(unsigned s) {
  unsigned u = (s & 0x80000000u) ? (s ^ 0x80000000u) : ~s;
  return __uint_as_float(u);
}

static __device__ __forceinline__ void gload_lds16(const unsigned short* g, unsigned short* l) {
  __builtin_amdgcn_global_load_lds(
      (const __attribute__((address_space(1))) void*)g,
      (__attribute__((address_space(3))) void*)l, 16, 0, 0);
}

// ---------------- Kernel 1: l2-normalize rows -> bf16 ----------------
__global__ __launch_bounds__(256)
void k_normalize(const float* __restrict__ z, const float* __restrict__ cb,
                 unsigned short* __restrict__ zf, unsigned short* __restrict__ cbf) {
  const int bid = blockIdx.x;
  const float* src;
  unsigned short* dst;
  if (bid < M_ROWS) {
    src = z + (size_t)bid * D_DIM;
    dst = zf + (size_t)bid * D_DIM;
  } else {
    const int r = bid - M_ROWS;
    src = cb + (size_t)r * D_DIM;
    dst = cbf + (size_t)r * D_DIM;
  }
  const int t = threadIdx.x;
  const float4 v = ((const float4*)src)[t];
  float ss = v.x * v.x + v.y * v.y + v.z * v.z + v.w * v.w;
#pragma unroll
  for (int off = 32; off > 0; off >>= 1) ss += __shfl_down(ss, off, 64);
  __shared__ float sp[4];
  if ((t & 63) == 0) sp[t >> 6] = ss;
  __syncthreads();
  const float tot = sp[0] + sp[1] + sp[2] + sp[3];
  const float invn = 1.0f / sqrtf(tot + 1e-12f);
  ushort4 o;
  o.x = f2bf(v.x * invn);
  o.y = f2bf(v.y * invn);
  o.z = f2bf(v.z * invn);
  o.w = f2bf(v.w * invn);
  ((ushort4*)dst)[t] = o;
}

// ---------------- Kernel 2: fused bf16 GEMM (swapped) + register top-8 ----------------
// D = Cf_tile (128 cb) x Zf_tile^T (128 z): D-row = cb col, D-col = z row.
// Lane (per nj): one z row, 16 cb values (4 mi x 4 regs) -> lane-local top-8.
__global__ __launch_bounds__(256, 2)
void k_gemm_topk(const unsigned short* __restrict__ zf,
                 const unsigned short* __restrict__ cbf,
                 unsigned* __restrict__ part) {
  __shared__ unsigned short smem[4][MTILE * BK];  // [0..1]=Z dbuf, [2..3]=C dbuf (32 KB)

  const int tid  = threadIdx.x;
  const int lane = tid & 63;
  const int wid  = tid >> 6;
  const int wc   = wid & 1;    // cb-dir wave (2)
  const int wz   = wid >> 1;   // z-dir wave (2)
  const int lo   = lane & 15;
  const int hi   = lane >> 4;

  // XCD-aware remap: xcd = wgid&7 (round-robin assumption); 2 XCDs per split ->
  // each XCD's L2 holds one 2MB codebook slab.
  const int wgid  = blockIdx.x + (int)gridDim.x * blockIdx.y;
  const int xcd   = wgid & 7;
  const int split = xcd >> 1;
  const int mtile = ((wgid >> 3) << 1) + (xcd & 1);
  const int rbase = mtile * MTILE;
  const int cbase = split * COLS_PER_SPLIT;

  // fragment LDS element offsets (both operands: row/col = lo, k-chunk = hi,
  // slot xor-swizzled by row&3)
  int coff[4], zoff[4];
#pragma unroll
  for (int mi = 0; mi < 4; ++mi) {
    const int r = wc * 64 + mi * 16 + lo;
    coff[mi] = r * BK + ((hi ^ (r & 3)) << 3);
  }
#pragma unroll
  for (int nj = 0; nj < 4; ++nj) {
    const int r = wz * 64 + nj * 16 + lo;
    zoff[nj] = r * BK + ((hi ^ (r & 3)) << 3);
  }

  // staging: slot = tid (row tid>>2, kslot tid&3) and slot+256 (row+64).
  // LDS dest linear; global source pre-swizzled (kslot ^ (row&3)).
  const int srow = tid >> 2;
  const int ksrc = ((tid & 3) ^ (srow & 3)) << 3;
  const long srcZ = (long)(rbase + srow) * D_DIM + ksrc;
  const long srcC = (long)(cbase + srow) * D_DIM + ksrc;

  f32x4 acc[4][4];
#pragma unroll
  for (int mi = 0; mi < 4; ++mi)
#pragma unroll
    for (int nj = 0; nj < 4; ++nj) acc[mi][nj] = (f32x4){0.f, 0.f, 0.f, 0.f};

  unsigned tk[4][8];
  unsigned tkmin[4];
  float    tminf[4];
#pragma unroll
  for (int l = 0; l < 4; ++l) {
    tkmin[l] = 0u;
    tminf[l] = -__builtin_inff();
#pragma unroll
    for (int q = 0; q < 8; ++q) tk[l][q] = 0u;
  }

  auto STAGE = [&](int g1) {
    const int b = g1 & 1;
    const long kb = (long)((g1 & (KSTEPS - 1)) << 5);
    const long cc = (long)(g1 >> 5) * (NTILE * D_DIM);
    gload_lds16(zf + srcZ + kb,                 &smem[b][tid * 8]);
    gload_lds16(zf + srcZ + 64 * D_DIM + kb,    &smem[b][2048 + tid * 8]);
    gload_lds16(cbf + srcC + cc + kb,           &smem[2 + b][tid * 8]);
    gload_lds16(cbf + srcC + cc + 64 * D_DIM + kb, &smem[2 + b][2048 + tid * 8]);
  };

  auto COMPUTE = [&](int b) {
    const unsigned short* Z = smem[b];
    const unsigned short* C = smem[2 + b];
    short8 cf[4], zr[4];
#pragma unroll
    for (int mi = 0; mi < 4; ++mi) cf[mi] = *(const short8*)(C + coff[mi]);
#pragma unroll
    for (int nj = 0; nj < 4; ++nj) zr[nj] = *(const short8*)(Z + zoff[nj]);
#pragma unroll
    for (int mi = 0; mi < 4; ++mi)
#pragma unroll
      for (int nj = 0; nj < 4; ++nj)
        acc[mi][nj] = __builtin_amdgcn_mfma_f32_16x16x32_bf16(cf[mi], zr[nj], acc[mi][nj], 0, 0, 0);
  };

  STAGE(0);
  __syncthreads();

  for (int g = 0; g < GITERS; ++g) {
    if (g + 1 < GITERS) STAGE(g + 1);
    COMPUTE(g & 1);
    __syncthreads();

    if ((g & (KSTEPS - 1)) == (KSTEPS - 1)) {          // chunk complete: register top-k
      const int cfb = cbase + (g >> 5) * NTILE + wc * 64 + hi * 4;
#pragma unroll
      for (int nj = 0; nj < 4; ++nj) {
#pragma unroll
        for (int mi = 0; mi < 4; ++mi) {
#pragma unroll
          for (int r = 0; r < 4; ++r) {
            const float v = acc[mi][nj][r];
            // NOTE: must be !(v <= t), NOT (v > t): while the table still has
            // empty (key=0) slots, tminf is sortable2f(0) = NaN; !(v<=NaN) is
            // true -> falls through to the exact u32 key check. (v > NaN) is
            // false and permanently starves the table (round-2 bug).
            if (!(v <= tminf[nj])) {
              const unsigned key = (f2sortable(v) & ~0xFFFu) | (unsigned)(cfb + mi * 16 + r);
              if (key > tkmin[nj]) {
                int ms = 0;
                unsigned mv = tk[nj][0];
#pragma unroll
                for (int q = 1; q < 8; ++q) { if (tk[nj][q] < mv) { mv = tk[nj][q]; ms = q; } }
#pragma unroll
                for (int q = 0; q < 8; ++q) tk[nj][q] = (q == ms) ? key : tk[nj][q];
                mv = tk[nj][0];
#pragma unroll
                for (int q = 1; q < 8; ++q) mv = (tk[nj][q] < mv) ? tk[nj][q] : mv;
                tkmin[nj] = mv;
                tminf[nj] = sortable2f(mv & ~0xFFFu);
              }
            }
            acc[mi][nj][r] = 0.f;
          }
        }
      }
    }
  }

  // final merge: per z row, 8 lanes x 8 keys -> LDS (aliases smem), then top-8 scan
  __syncthreads();
  unsigned* mrg = (unsigned*)smem;   // [128][64]
  {
    const int slot = wc * 4 + hi;
#pragma unroll
    for (int nj = 0; nj < 4; ++nj) {
      const int zrow = wz * 64 + nj * 16 + lo;
#pragma unroll
      for (int q = 0; q < 8; ++q) mrg[zrow * 64 + slot * 8 + q] = tk[nj][q];
    }
  }
  __syncthreads();
  if (tid < MTILE) {
    const unsigned* c = mrg + tid * 64;
    unsigned top[8];
#pragma unroll
    for (int p = 0; p < 8; ++p) top[p] = 0u;
    unsigned tmin = 0u;
    for (int q0 = 0; q0 < 64; ++q0) {
      const unsigned k = c[(q0 + tid) & 63];   // rotate to avoid bank conflicts
      if (k > tmin) {
        int ms = 0;
        unsigned mv = top[0];
#pragma unroll
        for (int q = 1; q < 8; ++q) { if (top[q] < mv) { mv = top[q]; ms = q; } }
#pragma unroll
        for (int q = 0; q < 8; ++q) top[q] = (q == ms) ? k : top[q];
        mv = top[0];
#pragma unroll
        for (int q = 1; q < 8; ++q) mv = (top[q] < mv) ? top[q] : mv;
        tmin = mv;
      }
    }
    unsigned* dst = part + ((size_t)(rbase + tid) * NSPLIT + split) * 8;
#pragma unroll
    for (int p = 0; p < 8; ++p) dst[p] = top[p];
  }
}

// ---------------- Kernel 3: merge splits, softmax, gather E, gate ----------------
__global__ __launch_bounds__(256)
void k_gate(const unsigned* __restrict__ part, const float* __restrict__ target,
            const float* __restrict__ E, float* __restrict__ out) {
  const int row = blockIdx.x;
  const int t = threadIdx.x;
  __shared__ float s_alpha[8];
  __shared__ int s_idx[8];
  __shared__ unsigned s_key[8];

  if (t < 32) {
    unsigned k = part[(size_t)row * 32 + t];
#pragma unroll
    for (int p = 0; p < 8; ++p) {
      unsigned m = k;
#pragma unroll
      for (int off = 16; off > 0; off >>= 1) {
        const unsigned o = __shfl_xor(m, off, 32);
        m = (m > o) ? m : o;
      }
      if (k == m) { s_key[p] = k; k = 0u; }  // keys distinct (idx in low bits)
    }
  }
  __syncthreads();
  if (t < 8) {
    const unsigned key = s_key[t];
    const float val  = 10.0f * sortable2f(key & ~0xFFFu);
    const float vmax = 10.0f * sortable2f(s_key[0] & ~0xFFFu);
    const float e = expf(val - vmax);
    float s = e;
#pragma unroll
    for (int off = 4; off > 0; off >>= 1) s += __shfl_xor(s, off, 8);
    s_alpha[t] = e / s;
    s_idx[t] = (int)(key & 0xFFFu);
  }
  __syncthreads();

  float4 g = {0.f, 0.f, 0.f, 0.f};
#pragma unroll
  for (int p = 0; p < 8; ++p) {
    const float a = s_alpha[p];
    const float4 e4 = ((const float4*)E)[(size_t)s_idx[p] * 256 + t];
    g.x += a * e4.x;
    g.y += a * e4.y;
    g.z += a * e4.z;
    g.w += a * e4.w;
  }
  const float4 tg = ((const float4*)target)[(size_t)row * 256 + t];
  float4 o;
  o.x = tg.x * (1.f + g.x);
  o.y = tg.y * (1.f + g.y);
  o.z = tg.z * (1.f + g.z);
  o.w = tg.w * (1.f + g.w);
  ((float4*)out)[(size_t)row * 256 + t] = o;
}

extern "C" void kernel_launch(void* const* d_in, const int* in_sizes, int n_in,
                              void* d_out, int out_size, void* d_ws, size_t ws_size,
                              hipStream_t stream) {
  const float* z      = (const float*)d_in[0];
  const float* target = (const float*)d_in[1];
  const float* cb     = (const float*)d_in[2];
  const float* E      = (const float*)d_in[3];
  float* out = (float*)d_out;

  // d_out doubles as scratch for the bf16 normalized matrices (dead before k_gate writes)
  unsigned short* zf  = (unsigned short*)d_out;                       // 32 MB
  unsigned short* cbf = (unsigned short*)((char*)d_out + 33554432);   // 8 MB @ +32MB
  unsigned* part = (unsigned*)d_ws;                                   // 2 MB

  k_normalize<<<dim3(M_ROWS + K_CB), dim3(256), 0, stream>>>(z, cb, zf, cbf);
  k_gemm_topk<<<dim3(MBLOCKS, NSPLIT), dim3(256), 0, stream>>>(zf, cbf, part);
  k_gate<<<dim3(M_ROWS), dim3(256), 0, stream>>>(part, target, E, out);
}